// Round 1
// baseline (5894.813 us; speedup 1.0000x reference)
//
#include <hip/hip_runtime.h>
#include <hip/hip_bf16.h>
#include <math.h>

// ---------------------------------------------------------------------------
// GCN forward: 2x GCNConv(sym-norm, self-loops) + mean-pool + 2-layer MLP head
// Round 1: correctness-first fp32. Edge aggregation via global fp32 atomics.
// ---------------------------------------------------------------------------

__global__ void deg_kernel(const int* __restrict__ ei, int E, float* __restrict__ deg) {
    int e = blockIdx.x * blockDim.x + threadIdx.x;
    if (e < E) atomicAdd(&deg[ei[E + e]], 1.0f);
}

__global__ void dinv_kernel(float* __restrict__ deg, int n) {
    int i = blockIdx.x * blockDim.x + threadIdx.x;
    if (i < n) deg[i] = rsqrtf(deg[i] + 1.0f);   // +1 for self-loop; always >= 1
}

// C[N,128] = A[N,K] @ W[K,128]. 32 rows/block, 256 threads.
// thread t: col = t&127, half = t>>7 -> rows half*16 .. half*16+15.
// x tile staged in LDS (contiguous rows -> flat float4 copy); LDS reads are
// broadcast within a wave (all 64 lanes share the same row address).
template<int K>
__global__ __launch_bounds__(256) void gemm_kernel(const float* __restrict__ A,
                                                   const float* __restrict__ W,
                                                   float* __restrict__ C) {
    __shared__ float xs[32 * K];
    const int rowbase = blockIdx.x * 32;
    const float4* Ag = (const float4*)(A + (size_t)rowbase * K);
    float4* xs4 = (float4*)xs;
    for (int i = threadIdx.x; i < 32 * K / 4; i += 256) xs4[i] = Ag[i];
    __syncthreads();

    const int c = threadIdx.x & 127;
    const int h = threadIdx.x >> 7;
    float acc[16];
#pragma unroll
    for (int j = 0; j < 16; ++j) acc[j] = 0.0f;

    for (int k = 0; k < K; k += 4) {
        const float w0 = W[(k + 0) * 128 + c];
        const float w1 = W[(k + 1) * 128 + c];
        const float w2 = W[(k + 2) * 128 + c];
        const float w3 = W[(k + 3) * 128 + c];
#pragma unroll
        for (int j = 0; j < 16; ++j) {
            const float4 xv = *(const float4*)&xs[(h * 16 + j) * K + k];
            acc[j] += xv.x * w0 + xv.y * w1 + xv.z * w2 + xv.w * w3;
        }
    }
#pragma unroll
    for (int j = 0; j < 16; ++j)
        C[(size_t)(rowbase + h * 16 + j) * 128 + c] = acc[j];
}

// out[dst] += pre[src] * dinv[src]*dinv[dst]. 32 lanes/edge (float4 each),
// 8 edges per 256-thread block.
__global__ __launch_bounds__(256) void edge_agg_kernel(const float* __restrict__ pre,
                                                       const float* __restrict__ dinv,
                                                       const int* __restrict__ ei, int E,
                                                       float* __restrict__ out) {
    int e = blockIdx.x * 8 + (threadIdx.x >> 5);
    if (e >= E) return;
    const int lane = threadIdx.x & 31;
    const int s = ei[e];
    const int d = ei[E + e];
    const float nrm = dinv[s] * dinv[d];
    const float4 v = ((const float4*)(pre + (size_t)s * 128))[lane];
    float* drow = out + (size_t)d * 128 + lane * 4;
    atomicAdd(drow + 0, v.x * nrm);
    atomicAdd(drow + 1, v.y * nrm);
    atomicAdd(drow + 2, v.z * nrm);
    atomicAdd(drow + 3, v.w * nrm);
}

// agg = [elu](agg + pre*dinv^2 + bias)   (self-loop message + bias [+ ELU])
template<int DO_ELU>
__global__ __launch_bounds__(256) void finalize_kernel(float* __restrict__ agg,
                                                       const float* __restrict__ pre,
                                                       const float* __restrict__ dinv,
                                                       const float* __restrict__ bias,
                                                       int n) {
    int idx = blockIdx.x * 256 + threadIdx.x;      // float4 index
    if (idx >= n * 32) return;
    const int node = idx >> 5;
    const int f4   = idx & 31;
    const float di = dinv[node];
    const float w  = di * di;
    float4 a = ((float4*)agg)[idx];
    const float4 p = ((const float4*)pre)[idx];
    const float4 b = ((const float4*)bias)[f4];
    a.x += p.x * w + b.x;
    a.y += p.y * w + b.y;
    a.z += p.z * w + b.z;
    a.w += p.w * w + b.w;
    if (DO_ELU) {
        a.x = a.x > 0.0f ? a.x : expm1f(a.x);
        a.y = a.y > 0.0f ? a.y : expm1f(a.y);
        a.z = a.z > 0.0f ? a.z : expm1f(a.z);
        a.w = a.w > 0.0f ? a.w : expm1f(a.w);
    }
    ((float4*)agg)[idx] = a;
}

// batch is sorted: per 512-node chunk, accumulate runs in registers and emit
// one atomicAdd per (run, feature). Thread = feature (128 threads).
__global__ __launch_bounds__(128) void pool_kernel(const float* __restrict__ h,
                                                   const int* __restrict__ batch, int n,
                                                   float* __restrict__ pooled,
                                                   float* __restrict__ cnt) {
    const int f = threadIdx.x;
    int start = blockIdx.x * 512;
    if (start >= n) return;
    int end = min(start + 512, n);
    int cur = batch[start];
    int runstart = start;
    float acc = 0.0f;
    for (int i = start; i < end; ++i) {
        int b = batch[i];
        if (b != cur) {
            atomicAdd(&pooled[cur * 128 + f], acc);
            if (f == 0) atomicAdd(&cnt[cur], (float)(i - runstart));
            acc = 0.0f; cur = b; runstart = i;
        }
        acc += h[(size_t)i * 128 + f];
    }
    atomicAdd(&pooled[cur * 128 + f], acc);
    if (f == 0) atomicAdd(&cnt[cur], (float)(end - runstart));
}

// 64 graphs, one thread each: z=[pooled/cnt, stats] -> relu(z@Wf1+bf1) -> @Wf2+bf2
// -> log_softmax.
__global__ __launch_bounds__(64) void head_kernel(const float* __restrict__ pooled,
                                                  const float* __restrict__ cnt,
                                                  const float* __restrict__ stats,
                                                  const float* __restrict__ Wf1,
                                                  const float* __restrict__ bf1,
                                                  const float* __restrict__ Wf2,
                                                  const float* __restrict__ bf2,
                                                  float* __restrict__ out) {
    __shared__ float w1s[138 * 20];
    __shared__ float w2s[20 * 5];
    for (int i = threadIdx.x; i < 138 * 20; i += 64) w1s[i] = Wf1[i];
    for (int i = threadIdx.x; i < 100; i += 64) w2s[i] = Wf2[i];
    __syncthreads();
    const int g = threadIdx.x;

    float z[138];
    const float inv = 1.0f / fmaxf(cnt[g], 1.0f);
    for (int i = 0; i < 128; ++i) z[i] = pooled[g * 128 + i] * inv;
    for (int i = 0; i < 10; ++i)  z[128 + i] = stats[g * 10 + i];

    float t[20];
    for (int j = 0; j < 20; ++j) {
        float a = bf1[j];
        for (int i = 0; i < 138; ++i) a += z[i] * w1s[i * 20 + j];
        t[j] = fmaxf(a, 0.0f);
    }
    float o[5];
    for (int j = 0; j < 5; ++j) {
        float a = bf2[j];
        for (int i = 0; i < 20; ++i) a += t[i] * w2s[i * 5 + j];
        o[j] = a;
    }
    float m = o[0];
    for (int j = 1; j < 5; ++j) m = fmaxf(m, o[j]);
    float s = 0.0f;
    for (int j = 0; j < 5; ++j) s += expf(o[j] - m);
    const float ls = logf(s) + m;
    for (int j = 0; j < 5; ++j) out[g * 5 + j] = o[j] - ls;
}

static inline size_t align_up(size_t v, size_t a) { return (v + a - 1) & ~(a - 1); }

extern "C" void kernel_launch(void* const* d_in, const int* in_sizes, int n_in,
                              void* d_out, int out_size, void* d_ws, size_t ws_size,
                              hipStream_t stream) {
    const float* x     = (const float*)d_in[0];
    const int*   ei    = (const int*)d_in[1];    // (2,E) flat: [src | dst]
    const int*   batch = (const int*)d_in[2];
    // d_in[3] = eig (unused by reference)
    const float* stats = (const float*)d_in[4];
    const float* W1  = (const float*)d_in[5];
    const float* b1  = (const float*)d_in[6];
    const float* W2  = (const float*)d_in[7];
    const float* b2  = (const float*)d_in[8];
    const float* Wf1 = (const float*)d_in[9];
    const float* bf1 = (const float*)d_in[10];
    const float* Wf2 = (const float*)d_in[11];
    const float* bf2 = (const float*)d_in[12];
    float* out = (float*)d_out;

    const int N = in_sizes[2];
    const int E = in_sizes[1] / 2;

    // workspace layout
    char* ws = (char*)d_ws;
    size_t o = 0;
    float* dinv = (float*)(ws + o);  o = align_up(o + (size_t)N * 4, 4096);
    float* bufA = (float*)(ws + o);  o = align_up(o + (size_t)N * 128 * 4, 4096);
    float* bufB = (float*)(ws + o);  o = align_up(o + (size_t)N * 128 * 4, 4096);
    float* pooled = (float*)(ws + o); o = align_up(o + 64 * 128 * 4, 256);
    float* cnt    = (float*)(ws + o); o = align_up(o + 64 * 4, 256);
    (void)ws_size; (void)n_in; (void)out_size;

    const size_t featBytes = (size_t)N * 128 * 4;

    // zero accumulators
    hipMemsetAsync(dinv, 0, (size_t)N * 4, stream);
    hipMemsetAsync(bufB, 0, featBytes, stream);
    hipMemsetAsync(pooled, 0, 64 * 128 * 4 + 256, stream);  // pooled + pad; cnt next
    hipMemsetAsync(cnt, 0, 64 * 4, stream);

    // degrees -> dinv
    deg_kernel<<<(E + 255) / 256, 256, 0, stream>>>(ei, E, dinv);
    dinv_kernel<<<(N + 255) / 256, 256, 0, stream>>>(dinv, N);

    // layer 1: pre = x @ W1 ; agg edges ; + self-loop + b1 ; elu
    gemm_kernel<64><<<N / 32, 256, 0, stream>>>(x, W1, bufA);
    edge_agg_kernel<<<(E + 7) / 8, 256, 0, stream>>>(bufA, dinv, ei, E, bufB);
    finalize_kernel<1><<<((size_t)N * 32 + 255) / 256, 256, 0, stream>>>(bufB, bufA, dinv, b1, N);

    // layer 2: pre = h1 @ W2 ; re-zero agg buf ; agg ; + self-loop + b2
    gemm_kernel<128><<<N / 32, 256, 0, stream>>>(bufB, W2, bufA);
    hipMemsetAsync(bufB, 0, featBytes, stream);
    edge_agg_kernel<<<(E + 7) / 8, 256, 0, stream>>>(bufA, dinv, ei, E, bufB);
    finalize_kernel<0><<<((size_t)N * 32 + 255) / 256, 256, 0, stream>>>(bufB, bufA, dinv, b2, N);

    // mean pool (batch sorted) + head
    pool_kernel<<<(N + 511) / 512, 128, 0, stream>>>(bufB, batch, N, pooled, cnt);
    head_kernel<<<1, 64, 0, stream>>>(pooled, cnt, stats, Wf1, bf1, Wf2, bf2, out);
}

// Round 2
// 1019.750 us; speedup vs baseline: 5.7806x; 5.7806x over previous
//
#include <hip/hip_runtime.h>
#include <hip/hip_bf16.h>
#include <math.h>

// ---------------------------------------------------------------------------
// GCN forward: 2x GCNConv(sym-norm, self-loops) + mean-pool + 2-layer MLP head
// Round 2: dst-CSR built on device; pull-style aggregation (zero atomics in
// the hot path), finalize (self-loop + bias + ELU) fused into aggregation.
// ---------------------------------------------------------------------------

__global__ void count_kernel(const int* __restrict__ ei, int E, int* __restrict__ cnt) {
    int e = blockIdx.x * blockDim.x + threadIdx.x;
    if (e < E) atomicAdd(&cnt[ei[E + e]], 1);
}

__global__ void dinv_kernel(const int* __restrict__ cnt, float* __restrict__ dinv, int n) {
    int i = blockIdx.x * blockDim.x + threadIdx.x;
    if (i < n) dinv[i] = rsqrtf((float)cnt[i] + 1.0f);   // +1 self-loop
}

// Exclusive scan of cnt[0..n-1] -> rowptr[0..n]. Single block, 1024 threads,
// each thread serially owns a ~n/1024 chunk; Hillis-Steele scan of partials.
__global__ __launch_bounds__(1024) void scan_kernel(const int* __restrict__ cnt, int n,
                                                    int* __restrict__ rowptr) {
    __shared__ int psum[1024];
    const int t = threadIdx.x;
    const int chunk = (n + 1023) / 1024;
    const int lo = t * chunk;
    const int hi = min(lo + chunk, n);
    int s = 0;
    for (int i = lo; i < hi; ++i) s += cnt[i];
    psum[t] = s;
    __syncthreads();
    for (int d = 1; d < 1024; d <<= 1) {
        int v = (t >= d) ? psum[t - d] : 0;
        __syncthreads();
        psum[t] += v;
        __syncthreads();
    }
    int run = psum[t] - s;               // exclusive offset for this chunk
    for (int i = lo; i < hi; ++i) { rowptr[i] = run; run += cnt[i]; }
    if (hi == n) rowptr[n] = run;        // total == E (also hit by empty chunks)
}

// Bucket edges by dst. adjw[pos] = (src as int bits, dinv[src]*dinv[dst]).
__global__ void scatter_kernel(const int* __restrict__ ei, int E,
                               const int* __restrict__ rowptr,
                               int* __restrict__ fill,
                               const float* __restrict__ dinv,
                               float2* __restrict__ adjw) {
    int e = blockIdx.x * blockDim.x + threadIdx.x;
    if (e >= E) return;
    const int s = ei[e];
    const int d = ei[E + e];
    const int pos = rowptr[d] + atomicAdd(&fill[d], 1);
    float2 aw;
    aw.x = __int_as_float(s);
    aw.y = dinv[s] * dinv[d];
    adjw[pos] = aw;
}

// Pull aggregation, one wave (64 lanes) per node, lane owns 2 features.
// out[node] = [elu]( sum_{e in CSR[node]} pre[src_e]*norm_e
//                    + pre[node]*dinv[node]^2 + bias )
template<int DO_ELU>
__global__ __launch_bounds__(256) void agg_kernel(const float* __restrict__ pre,
                                                  const float2* __restrict__ adjw,
                                                  const int* __restrict__ rowptr,
                                                  const float* __restrict__ dinv,
                                                  const float* __restrict__ bias,
                                                  int n, float* __restrict__ out) {
    const int node = blockIdx.x * 4 + (threadIdx.x >> 6);
    if (node >= n) return;
    const int lane = threadIdx.x & 63;
    const int beg = rowptr[node];
    const int end = rowptr[node + 1];
    const float di = dinv[node];
    const float2 p = *(const float2*)&pre[(size_t)node * 128 + lane * 2];
    const float2 b = *(const float2*)&bias[lane * 2];
    float2 acc;
    acc.x = p.x * di * di + b.x;
    acc.y = p.y * di * di + b.y;
    for (int e = beg; e < end; ++e) {
        const float2 aw = adjw[e];                 // 8B broadcast (wave-uniform)
        const int s = __float_as_int(aw.x);
        const float w = aw.y;
        const float2 v = *(const float2*)&pre[(size_t)s * 128 + lane * 2];
        acc.x += v.x * w;
        acc.y += v.y * w;
    }
    if (DO_ELU) {
        acc.x = acc.x > 0.0f ? acc.x : expm1f(acc.x);
        acc.y = acc.y > 0.0f ? acc.y : expm1f(acc.y);
    }
    *(float2*)&out[(size_t)node * 128 + lane * 2] = acc;
}

// C[N,128] = A[N,K] @ W[K,128]. 32 rows/block, 256 threads.
template<int K>
__global__ __launch_bounds__(256) void gemm_kernel(const float* __restrict__ A,
                                                   const float* __restrict__ W,
                                                   float* __restrict__ C) {
    __shared__ float xs[32 * K];
    const int rowbase = blockIdx.x * 32;
    const float4* Ag = (const float4*)(A + (size_t)rowbase * K);
    float4* xs4 = (float4*)xs;
    for (int i = threadIdx.x; i < 32 * K / 4; i += 256) xs4[i] = Ag[i];
    __syncthreads();

    const int c = threadIdx.x & 127;
    const int h = threadIdx.x >> 7;
    float acc[16];
#pragma unroll
    for (int j = 0; j < 16; ++j) acc[j] = 0.0f;

    for (int k = 0; k < K; k += 4) {
        const float w0 = W[(k + 0) * 128 + c];
        const float w1 = W[(k + 1) * 128 + c];
        const float w2 = W[(k + 2) * 128 + c];
        const float w3 = W[(k + 3) * 128 + c];
#pragma unroll
        for (int j = 0; j < 16; ++j) {
            const float4 xv = *(const float4*)&xs[(h * 16 + j) * K + k];
            acc[j] += xv.x * w0 + xv.y * w1 + xv.z * w2 + xv.w * w3;
        }
    }
#pragma unroll
    for (int j = 0; j < 16; ++j)
        C[(size_t)(rowbase + h * 16 + j) * 128 + c] = acc[j];
}

// batch is sorted: per 512-node chunk, accumulate runs in registers and emit
// one atomicAdd per (run, feature). Thread = feature (128 threads).
__global__ __launch_bounds__(128) void pool_kernel(const float* __restrict__ h,
                                                   const int* __restrict__ batch, int n,
                                                   float* __restrict__ pooled,
                                                   float* __restrict__ cnt) {
    const int f = threadIdx.x;
    int start = blockIdx.x * 512;
    if (start >= n) return;
    int end = min(start + 512, n);
    int cur = batch[start];
    int runstart = start;
    float acc = 0.0f;
    for (int i = start; i < end; ++i) {
        int b = batch[i];
        if (b != cur) {
            atomicAdd(&pooled[cur * 128 + f], acc);
            if (f == 0) atomicAdd(&cnt[cur], (float)(i - runstart));
            acc = 0.0f; cur = b; runstart = i;
        }
        acc += h[(size_t)i * 128 + f];
    }
    atomicAdd(&pooled[cur * 128 + f], acc);
    if (f == 0) atomicAdd(&cnt[cur], (float)(end - runstart));
}

// 64 graphs, one thread each: z=[pooled/cnt, stats] -> relu(z@Wf1+bf1) -> @Wf2+bf2
// -> log_softmax.
__global__ __launch_bounds__(64) void head_kernel(const float* __restrict__ pooled,
                                                  const float* __restrict__ cnt,
                                                  const float* __restrict__ stats,
                                                  const float* __restrict__ Wf1,
                                                  const float* __restrict__ bf1,
                                                  const float* __restrict__ Wf2,
                                                  const float* __restrict__ bf2,
                                                  float* __restrict__ out) {
    __shared__ float w1s[138 * 20];
    __shared__ float w2s[20 * 5];
    for (int i = threadIdx.x; i < 138 * 20; i += 64) w1s[i] = Wf1[i];
    for (int i = threadIdx.x; i < 100; i += 64) w2s[i] = Wf2[i];
    __syncthreads();
    const int g = threadIdx.x;

    float z[138];
    const float inv = 1.0f / fmaxf(cnt[g], 1.0f);
    for (int i = 0; i < 128; ++i) z[i] = pooled[g * 128 + i] * inv;
    for (int i = 0; i < 10; ++i)  z[128 + i] = stats[g * 10 + i];

    float t[20];
    for (int j = 0; j < 20; ++j) {
        float a = bf1[j];
        for (int i = 0; i < 138; ++i) a += z[i] * w1s[i * 20 + j];
        t[j] = fmaxf(a, 0.0f);
    }
    float o[5];
    for (int j = 0; j < 5; ++j) {
        float a = bf2[j];
        for (int i = 0; i < 20; ++i) a += t[i] * w2s[i * 5 + j];
        o[j] = a;
    }
    float m = o[0];
    for (int j = 1; j < 5; ++j) m = fmaxf(m, o[j]);
    float s = 0.0f;
    for (int j = 0; j < 5; ++j) s += expf(o[j] - m);
    const float ls = logf(s) + m;
    for (int j = 0; j < 5; ++j) out[g * 5 + j] = o[j] - ls;
}

static inline size_t align_up(size_t v, size_t a) { return (v + a - 1) & ~(a - 1); }

extern "C" void kernel_launch(void* const* d_in, const int* in_sizes, int n_in,
                              void* d_out, int out_size, void* d_ws, size_t ws_size,
                              hipStream_t stream) {
    const float* x     = (const float*)d_in[0];
    const int*   ei    = (const int*)d_in[1];    // (2,E) flat: [src | dst]
    const int*   batch = (const int*)d_in[2];
    // d_in[3] = eig (unused by reference)
    const float* stats = (const float*)d_in[4];
    const float* W1  = (const float*)d_in[5];
    const float* b1  = (const float*)d_in[6];
    const float* W2  = (const float*)d_in[7];
    const float* b2  = (const float*)d_in[8];
    const float* Wf1 = (const float*)d_in[9];
    const float* bf1 = (const float*)d_in[10];
    const float* Wf2 = (const float*)d_in[11];
    const float* bf2 = (const float*)d_in[12];
    float* out = (float*)d_out;

    const int N = in_sizes[2];
    const int E = in_sizes[1] / 2;

    // workspace layout (~117 MB)
    char* ws = (char*)d_ws;
    size_t o = 0;
    float* dinv   = (float*)(ws + o);  o = align_up(o + (size_t)N * 4, 4096);
    int*   cnt    = (int*)(ws + o);    o = align_up(o + (size_t)N * 4, 4096);
    int*   fill   = (int*)(ws + o);    o = align_up(o + (size_t)N * 4, 4096);
    int*   rowptr = (int*)(ws + o);    o = align_up(o + (size_t)(N + 1) * 4, 4096);
    float2* adjw  = (float2*)(ws + o); o = align_up(o + (size_t)E * 8, 4096);
    float* bufA   = (float*)(ws + o);  o = align_up(o + (size_t)N * 128 * 4, 4096);
    float* bufB   = (float*)(ws + o);  o = align_up(o + (size_t)N * 128 * 4, 4096);
    float* pooled = (float*)(ws + o);  o = align_up(o + 64 * 128 * 4, 256);
    float* gcnt   = (float*)(ws + o);  o = align_up(o + 64 * 4, 256);
    (void)ws_size; (void)n_in; (void)out_size;

    // zero the small accumulators only
    hipMemsetAsync(cnt, 0, (size_t)N * 4, stream);
    hipMemsetAsync(fill, 0, (size_t)N * 4, stream);
    hipMemsetAsync(pooled, 0, 64 * 128 * 4, stream);
    hipMemsetAsync(gcnt, 0, 64 * 4, stream);

    // CSR build: count -> dinv -> scan -> scatter
    count_kernel<<<(E + 255) / 256, 256, 0, stream>>>(ei, E, cnt);
    dinv_kernel<<<(N + 255) / 256, 256, 0, stream>>>(cnt, dinv, N);
    scan_kernel<<<1, 1024, 0, stream>>>(cnt, N, rowptr);
    scatter_kernel<<<(E + 255) / 256, 256, 0, stream>>>(ei, E, rowptr, fill, dinv, adjw);

    // layer 1: pre = x @ W1 ; fused agg + self-loop + b1 + ELU
    gemm_kernel<64><<<N / 32, 256, 0, stream>>>(x, W1, bufA);
    agg_kernel<1><<<(N + 3) / 4, 256, 0, stream>>>(bufA, adjw, rowptr, dinv, b1, N, bufB);

    // layer 2: pre = h1 @ W2 ; fused agg + self-loop + b2
    gemm_kernel<128><<<N / 32, 256, 0, stream>>>(bufB, W2, bufA);
    agg_kernel<0><<<(N + 3) / 4, 256, 0, stream>>>(bufA, adjw, rowptr, dinv, b2, N, bufB);

    // mean pool (batch sorted) + head
    pool_kernel<<<(N + 511) / 512, 128, 0, stream>>>(bufB, batch, N, pooled, gcnt);
    head_kernel<<<1, 64, 0, stream>>>(pooled, gcnt, stats, Wf1, bf1, Wf2, bf2, out);
}